// Round 1
// baseline (1497.343 us; speedup 1.0000x reference)
//
#include <hip/hip_runtime.h>
#include <cstdint>
#include <cstddef>

// Problem constants
#define B_   1024
#define L_   64
#define H_   512

// Workspace layout (bytes). Required ws_size >= 16,257,024 (~15.6 MiB).
//  WB  : transposed bf16 weights  BT_j[n][k]  (j0: 512x512, j1-3: 512x1024)
//  SB  : state buffers bf16 [layer j][parity][B][H]
//  ACC : per-batch logprob accumulator fp32 [B]
//  H3F : fp32 copy of layer-3 activations [parity][B][H] for the logit dot
#define WB_OFF   0u
#define SB_OFF   3670016u
#define ACC_OFF  12058624u
#define H3F_OFF  12062720u

typedef __attribute__((ext_vector_type(8))) short short8;
typedef __attribute__((ext_vector_type(4))) float f32x4;

__device__ __forceinline__ unsigned short f2bf(float f) {
  unsigned u = __float_as_uint(f);
  u += 0x7fffu + ((u >> 16) & 1u);   // RNE
  return (unsigned short)(u >> 16);
}

__device__ __forceinline__ void async16(const void* g, void* l) {
  __builtin_amdgcn_global_load_lds(
      (const __attribute__((address_space(1))) void*)g,
      (__attribute__((address_space(3))) void*)l, 16, 0, 0);
}

// ---------------------------------------------------------------------------
// Init: transpose+convert weights fp32->bf16 [N][K], zero state + ACC.
// Blocks 0..447: 64x64 transpose tiles. Blocks 448..511: zero fill.
// ---------------------------------------------------------------------------
__global__ __launch_bounds__(256) void init_kernel(
    const float* __restrict__ Wc, const float* __restrict__ Win_rest,
    char* __restrict__ ws)
{
  const unsigned bb = blockIdx.x;
  const int tid = threadIdx.x;
  if (bb < 448u) {
    __shared__ float tile[64][65];
    int m, tt;
    if (bb < 64u) { m = 0; tt = (int)bb; }
    else { m = 1 + (int)((bb - 64u) >> 7); tt = (int)((bb - 64u) & 127u); }
    const int Km = (m == 0) ? 512 : 1024;
    const int nkt = Km >> 6;
    const int tk = tt % nkt, tn = tt / nkt;
    const int k0 = tk << 6, n0 = tn << 6;
    const int rr = tid >> 4, cc = (tid & 15) << 2;
#pragma unroll
    for (int qq = 0; qq < 4; ++qq) {
      const int row = rr + qq * 16;     // local k
      const int kg = k0 + row;
      const float* src;
      if (m == 0)        src = Wc + (size_t)kg * 512 + n0 + cc;
      else if (kg < 512) src = Wc + ((size_t)m * 512 + kg) * 512 + n0 + cc;
      else               src = Win_rest + ((size_t)(m - 1) * 512 + (kg - 512)) * 512 + n0 + cc;
      const float4 v = *(const float4*)src;
      tile[row][cc + 0] = v.x; tile[row][cc + 1] = v.y;
      tile[row][cc + 2] = v.z; tile[row][cc + 3] = v.w;
    }
    __syncthreads();
    unsigned short* dst = (unsigned short*)(ws + WB_OFF);
    const size_t base = (m == 0) ? 0 : (size_t)262144 + (size_t)(m - 1) * 524288;
#pragma unroll
    for (int qq = 0; qq < 4; ++qq) {
      const int nl = rr + qq * 16;
      const int kl = (tid & 15) << 2;
      ushort4 o;
      o.x = f2bf(tile[kl + 0][nl]); o.y = f2bf(tile[kl + 1][nl]);
      o.z = f2bf(tile[kl + 2][nl]); o.w = f2bf(tile[kl + 3][nl]);
      *(ushort4*)(dst + base + (size_t)(n0 + nl) * Km + k0 + kl) = o;
    }
  } else {
    // zero SB (8,388,608 B) + ACC (4,096 B) = 524,544 x 16 B
    f32x4* z = (f32x4*)(ws + SB_OFF);
    const unsigned idx = (bb - 448u) * 256u + (unsigned)tid;
    const f32x4 zero = {0.f, 0.f, 0.f, 0.f};
    for (unsigned u = idx; u < 524544u; u += 16384u) z[u] = zero;
  }
}

// ---------------------------------------------------------------------------
// One wavefront diagonal r. Cells (t = r - j, j) for j in [jlo, min(3,r)].
// GEMM blocks: cellidx = blk>>6; 64 tiles of 128x64 per cell.
// Out blocks (blk >= gemmBlocks): logprob for t = r-4 (4 rows per block).
// ---------------------------------------------------------------------------
__global__ __launch_bounds__(256) void round_kernel(
    int r, int jlo, int gemmBlocks,
    const int* __restrict__ x, const float* __restrict__ Win0,
    const float* __restrict__ bc, const float* __restrict__ Wout,
    const float* __restrict__ bout, char* __restrict__ ws,
    float* __restrict__ out)
{
  const int tid = threadIdx.x;
  const int wave = tid >> 6, lane = tid & 63;
  const unsigned short* WB = (const unsigned short*)(ws + WB_OFF);
  unsigned short* SB = (unsigned short*)(ws + SB_OFF);
  float* ACC = (float*)(ws + ACC_OFF);
  float* H3F = (float*)(ws + H3F_OFF);

  if ((int)blockIdx.x >= gemmBlocks) {
    // ---- logprob cell for t = r-4 (host guarantees r >= 4 here)
    const int t = r - 4;
    const int b = ((int)blockIdx.x - gemmBlocks) * 4 + wave;
    const float* h3 = H3F + (size_t)((r + 1) & 1) * (B_ * H_) + (size_t)b * H_;
    float z0 = 0.f, z1 = 0.f;
#pragma unroll
    for (int i = 0; i < 8; ++i) {
      const int n = lane * 8 + i;
      const float h = h3[n];
      z0 = fmaf(h, Wout[n * 2 + 0], z0);
      z1 = fmaf(h, Wout[n * 2 + 1], z1);
    }
#pragma unroll
    for (int off = 32; off > 0; off >>= 1) {
      z0 += __shfl_down(z0, off);
      z1 += __shfl_down(z1, off);
    }
    if (lane == 0) {
      z0 += bout[0]; z1 += bout[1];
      const float mx = fmaxf(z0, z1), mn = fminf(z0, z1);
      const float lse = mx + log1pf(expf(mn - mx));
      const int xt = x[b * L_ + t];
      float lp = ((xt == 0) ? z0 : z1) - lse;
      if (!(lp == lp)) lp = -35.0f;           // nan_to_num
      const float a = ACC[b] + lp;
      ACC[b] = a;
      if (t == 63) out[b] = 0.5f * a;         // LOG_PROB_FACTOR
    }
    return;
  }

  // ---- GEMM cell: C[128x64] = A[128xKc] * W[Kcx512] column slice
  __shared__ short Alds[2][128 * 32];
  __shared__ short Blds[2][64 * 32];

  const int cellidx = (int)blockIdx.x >> 6;
  const int j = jlo + cellidx;
  const int t = r - j;
  const int within = (int)blockIdx.x & 63;
  const int bm0 = (within >> 3) * 128;
  const int bn0 = (within & 7) * 64;
  const int Kc = (j == 0) ? 512 : 1024;
  const int nk = Kc >> 5;
  const unsigned short* Wj = WB + ((j == 0) ? 0u : (262144u + (unsigned)(j - 1) * 524288u));
  const int pprev = (r + 1) & 1, pcur = r & 1;
  const unsigned short* Ssrc = SB + (size_t)(j * 2 + pprev) * (B_ * H_);
  const unsigned short* Psrc = (j > 0) ? SB + (size_t)((j - 1) * 2 + pprev) * (B_ * H_)
                                       : (const unsigned short*)0;
  unsigned short* Dst = SB + (size_t)(j * 2 + pcur) * (B_ * H_);

  const int srow = lane >> 2;                        // staging row within 16-row segment
  const int schunk = (lane & 3) ^ ((lane >> 3) & 3); // XOR-swizzled source 16B chunk

  auto stage = [&](int kk, int pb) {
    const int k0 = kk << 5;
    const unsigned short* Asrc; int ak0;
    if (k0 < 512) { Asrc = Ssrc; ak0 = k0; } else { Asrc = Psrc; ak0 = k0 - 512; }
#pragma unroll
    for (int qq = 0; qq < 2; ++qq) {
      const int lrow = (wave * 2 + qq) * 16 + srow;
      async16(Asrc + (size_t)(bm0 + lrow) * H_ + ak0 + schunk * 8,
              &Alds[pb][(wave * 2 + qq) * 512 + lane * 8]);
    }
    {
      const int lrow = wave * 16 + srow;
      async16(Wj + (size_t)(bn0 + lrow) * Kc + k0 + schunk * 8,
              &Blds[pb][wave * 512 + lane * 8]);
    }
  };

  f32x4 acc[2][4] = {};
  const int q = lane >> 4, ln = lane & 15;
  const int cSwz = (ln >> 1) & 3;                    // == (row>>1)&3 for our rows

  stage(0, 0);
  for (int kk = 0; kk < nk; ++kk) {
    const int pb = kk & 1;
    __syncthreads();                 // drains vmcnt: stage(kk) complete; prev reads done
    if (kk + 1 < nk) stage(kk + 1, pb ^ 1);
    const short* Ab = &Alds[pb][0];
    const short* Bb = &Blds[pb][0];
    short8 af[2], bfr[4];
#pragma unroll
    for (int mt = 0; mt < 2; ++mt) {
      const int rr_ = wave * 32 + mt * 16 + ln;
      af[mt] = *(const short8*)(Ab + rr_ * 32 + (q ^ cSwz) * 8);
    }
#pragma unroll
    for (int nt = 0; nt < 4; ++nt) {
      const int rn = nt * 16 + ln;
      bfr[nt] = *(const short8*)(Bb + rn * 32 + (q ^ cSwz) * 8);
    }
#pragma unroll
    for (int mt = 0; mt < 2; ++mt)
#pragma unroll
      for (int nt = 0; nt < 4; ++nt)
        acc[mt][nt] = __builtin_amdgcn_mfma_f32_16x16x32_bf16(af[mt], bfr[nt], acc[mt][nt], 0, 0, 0);
  }

  // epilogue: bias (+ Win0 row for layer 0) + elu, store bf16 state (+ fp32 h3)
  const float* bcj = bc + j * H_;
  const int colbase = bn0 + ln;
#pragma unroll
  for (int mt = 0; mt < 2; ++mt) {
#pragma unroll
    for (int i = 0; i < 4; ++i) {
      const int brow = bm0 + wave * 32 + mt * 16 + q * 4 + i;
      int xprev = 0;
      if (j == 0 && t > 0) xprev = x[brow * L_ + (t - 1)];
#pragma unroll
      for (int nt = 0; nt < 4; ++nt) {
        const int col = colbase + nt * 16;
        float pre = acc[mt][nt][i] + bcj[col];
        if (j == 0 && t > 0) pre += Win0[xprev * H_ + col];
        const float h = (pre > 0.f) ? pre : expm1f(pre);
        Dst[(size_t)brow * H_ + col] = f2bf(h);
        if (j == 3) H3F[(size_t)pcur * (B_ * H_) + (size_t)brow * H_ + col] = h;
      }
    }
  }
}

// ---------------------------------------------------------------------------
extern "C" void kernel_launch(void* const* d_in, const int* in_sizes, int n_in,
                              void* d_out, int out_size, void* d_ws, size_t ws_size,
                              hipStream_t stream) {
  const int*   x        = (const int*)d_in[0];
  const float* Win0     = (const float*)d_in[1];
  const float* Win_rest = (const float*)d_in[2];
  const float* Wc       = (const float*)d_in[3];
  const float* bc       = (const float*)d_in[4];
  const float* Wout     = (const float*)d_in[5];
  const float* bout     = (const float*)d_in[6];
  float* out = (float*)d_out;
  char*  ws  = (char*)d_ws;

  init_kernel<<<512, 256, 0, stream>>>(Wc, Win_rest, ws);

  for (int r = 0; r <= 67; ++r) {
    const int jlo = (r > 63) ? (r - 63) : 0;
    const int jhi = (r < 3) ? r : 3;
    const int ncells = (jhi >= jlo) ? (jhi - jlo + 1) : 0;
    const int gemmBlocks = ncells * 64;
    const int outBlocks = (r >= 4) ? 256 : 0;
    round_kernel<<<gemmBlocks + outBlocks, 256, 0, stream>>>(
        r, jlo, gemmBlocks, x, Win0, bc, Wout, bout, ws, out);
  }
}